// Round 1
// 1265.946 us; speedup vs baseline: 1.2940x; 1.2940x over previous
//
#include <hip/hip_runtime.h>
#include <hip/hip_bf16.h>
#include <stdint.h>

#define XS 128
#define YS 128
#define ZS 8
#define NQ (XS*YS*ZS)        // 131072 queries
#define CDIM 128
#define NH 8
#define HD 16
#define DH 192
#define DW 640
#define NPIX (DH*DW)
#define NVPIX 10080          // 7680 + 1920 + 480

__device__ __forceinline__ float b2f(unsigned short u){
    union { unsigned int i; float f; } v; v.i = ((unsigned int)u) << 16; return v.f;
}
__device__ __forceinline__ unsigned short f2b(float f){
    __hip_bfloat16 h = __float2bfloat16(f);
    return *reinterpret_cast<unsigned short*>(&h);
}
// load 2 bf16 channels (4B) -> two floats
__device__ __forceinline__ void ld2(const unsigned short* p, float& a, float& b){
    unsigned int u = *reinterpret_cast<const unsigned int*>(p);
    a = b2f((unsigned short)(u & 0xffffu));
    b = b2f((unsigned short)(u >> 16));
}

// ---------------- inverse of K (3x3) and E (4x4), fp64, one thread ----------------
__global__ void inv_kernel(const float* __restrict__ K,
                           const float* __restrict__ E,
                           double* __restrict__ inv_out){
    if (threadIdx.x != 0 || blockIdx.x != 0) return;
    double k[3][3], e[4][4];
    for (int i=0;i<9;i++)  k[i/3][i%3] = (double)K[i];
    for (int i=0;i<16;i++) e[i/4][i%4] = (double)E[i];
    double det = k[0][0]*(k[1][1]*k[2][2]-k[1][2]*k[2][1])
               - k[0][1]*(k[1][0]*k[2][2]-k[1][2]*k[2][0])
               + k[0][2]*(k[1][0]*k[2][1]-k[1][1]*k[2][0]);
    double id = 1.0/det;
    double inv[3][3];
    inv[0][0]=(k[1][1]*k[2][2]-k[1][2]*k[2][1])*id;
    inv[0][1]=(k[0][2]*k[2][1]-k[0][1]*k[2][2])*id;
    inv[0][2]=(k[0][1]*k[1][2]-k[0][2]*k[1][1])*id;
    inv[1][0]=(k[1][2]*k[2][0]-k[1][0]*k[2][2])*id;
    inv[1][1]=(k[0][0]*k[2][2]-k[0][2]*k[2][0])*id;
    inv[1][2]=(k[0][2]*k[1][0]-k[0][0]*k[1][2])*id;
    inv[2][0]=(k[1][0]*k[2][1]-k[1][1]*k[2][0])*id;
    inv[2][1]=(k[0][1]*k[2][0]-k[0][0]*k[2][1])*id;
    inv[2][2]=(k[0][0]*k[1][1]-k[0][1]*k[1][0])*id;
    for (int i=0;i<9;i++) inv_out[i] = inv[i/3][i%3];
    double a[4][8];
    for (int i=0;i<4;i++){ for(int j=0;j<4;j++){ a[i][j]=e[i][j]; a[i][4+j]=(i==j)?1.0:0.0; } }
    for (int c=0;c<4;c++){
        int piv=c; double best=fabs(a[c][c]);
        for (int r=c+1;r<4;r++){ double v=fabs(a[r][c]); if (v>best){best=v;piv=r;} }
        if (piv!=c){ for (int j=0;j<8;j++){ double tmp=a[c][j]; a[c][j]=a[piv][j]; a[piv][j]=tmp; } }
        double pv = 1.0/a[c][c];
        for (int j=0;j<8;j++) a[c][j]*=pv;
        for (int r=0;r<4;r++){
            if (r==c) continue;
            double f=a[r][c];
            for(int j=0;j<8;j++) a[r][j]-=f*a[c][j];
        }
    }
    for (int i=0;i<16;i++) inv_out[9+i] = a[i/4][4 + (i%4)];
}

// ---------------- pix2vox + voxel mask ----------------
__global__ void mask_kernel(const float* __restrict__ depth,
                            const double* __restrict__ invm,
                            const float* __restrict__ vorigin,
                            unsigned char* __restrict__ mask){
    int tid = blockIdx.x*blockDim.x + threadIdx.x;
    if (tid >= NPIX) return;
    int gx = tid % DW, gy = tid / DW;
    double d  = (double)depth[tid];
    double X0 = (double)gx * d, X1 = (double)gy * d, X2 = d;
    double c0 = invm[0]*X0 + invm[1]*X1 + invm[2]*X2;
    double c1 = invm[3]*X0 + invm[4]*X1 + invm[5]*X2;
    double c2 = invm[6]*X0 + invm[7]*X1 + invm[8]*X2;
    const double* iE = invm + 9;
    double w0 = iE[0]*c0 + iE[1]*c1 + iE[2]*c2  + iE[3];
    double w1 = iE[4]*c0 + iE[5]*c1 + iE[6]*c2  + iE[7];
    double w2 = iE[8]*c0 + iE[9]*c1 + iE[10]*c2 + iE[11];
    double v0 = (w0-(double)vorigin[0])/0.4 - 0.5;
    double v1 = (w1-(double)vorigin[1])/0.4 - 0.5;
    double v2 = ((w2-(double)vorigin[2])/0.4 - 0.5) / 2.0;
    int xi = (int)v0, yi = (int)v1, zi = (int)v2;
    if (xi>=0 && xi<XS && yi>=0 && yi<YS && zi>=0 && zi<ZS)
        mask[(xi*YS + yi)*ZS + zi] = 1;
}

// ---------------- value = flat @ Wv.T + bv -> bf16, 4 pixels/block ----------------
// NEW: head-major layout value[h][pix][hd] so a head's 16 channels of a pixel
// are 32 contiguous bytes and x/x+1 bilinear corners share one 64B line.
__global__ __launch_bounds__(128)
void value_kernel(const float* __restrict__ f0,
                  const float* __restrict__ f1,
                  const float* __restrict__ f2,
                  const float* __restrict__ Wv,
                  const float* __restrict__ bv,
                  unsigned short* __restrict__ value){
    int p0 = blockIdx.x*4, t = threadIdx.x;
    __shared__ float fl[CDIM][4];
    const float* src; int hw, lp;
    if (p0 < 7680)      { src=f0; hw=7680; lp=p0; }
    else if (p0 < 9600) { src=f1; hw=1920; lp=p0-7680; }
    else                { src=f2; hw=480;  lp=p0-9600; }
    float4 v = *(const float4*)(src + t*hw + lp);
    fl[t][0]=v.x; fl[t][1]=v.y; fl[t][2]=v.z; fl[t][3]=v.w;
    __syncthreads();
    float bb = bv[t];
    float acc[4] = {bb,bb,bb,bb};
    const float4* wrow = (const float4*)(Wv + t*CDIM);
    #pragma unroll 8
    for (int kc=0; kc<32; ++kc){
        float4 w = wrow[kc];
        #pragma unroll
        for (int u=0;u<4;u++){
            float wu = (u==0)?w.x:(u==1)?w.y:(u==2)?w.z:w.w;
            float4 fv = *(const float4*)fl[kc*4+u];
            acc[0] += fv.x*wu; acc[1] += fv.y*wu; acc[2] += fv.z*wu; acc[3] += fv.w*wu;
        }
    }
    const int hh = t >> 4, cc = t & 15;
    #pragma unroll
    for (int i=0;i<4;i++)
        value[((size_t)hh*NVPIX + (size_t)(p0+i))*HD + cc] = f2b(acc[i]);
}

// ---------------- offsets+logits GEMM: [288 x len] bf16, transposed output ----------------
__global__ __launch_bounds__(256)
void offaw_kernel(const float* __restrict__ q_in,      // chunk base
                  const float* __restrict__ Woff,
                  const float* __restrict__ boff,
                  const float* __restrict__ Wattw,
                  const float* __restrict__ battw,
                  unsigned short* __restrict__ offawT, // [288][len]
                  int len){
    const int n0 = blockIdx.x * 64;
    const int t = threadIdx.x;
    __shared__ float Qs[64][129];
    for (int idx = t; idx < 64*CDIM; idx += 256){
        int n = idx >> 7, c = idx & 127;
        Qs[n][c] = q_in[(size_t)(n0+n)*CDIM + c];
    }
    __syncthreads();
    const int w = t >> 6, lane = t & 63;
    for (int g = 0; g < 6; ++g){
        const int j0 = w*72 + g*12;
        const float* Wb; const float* bb;
        if (j0 < 192){ Wb = Woff  + (size_t)j0*CDIM;       bb = boff  + j0; }
        else         { Wb = Wattw + (size_t)(j0-192)*CDIM; bb = battw + (j0-192); }
        float acc[12];
        #pragma unroll
        for (int r=0;r<12;r++) acc[r] = bb[r];
        #pragma unroll 2
        for (int kc = 0; kc < 32; ++kc){
            float q0 = Qs[lane][kc*4+0];
            float q1 = Qs[lane][kc*4+1];
            float q2 = Qs[lane][kc*4+2];
            float q3 = Qs[lane][kc*4+3];
            #pragma unroll
            for (int r=0;r<12;r++){
                float4 w4 = *(const float4*)(Wb + r*CDIM + kc*4);
                acc[r] += q0*w4.x + q1*w4.y + q2*w4.z + q3*w4.w;
            }
        }
        #pragma unroll
        for (int r=0;r<12;r++)
            offawT[(size_t)(j0+r)*len + n0 + lane] = f2b(acc[r]);
    }
}

// ---------------- sampling + Wout + LN + mask + transposed store ----------------
// Block: 256 threads, 8 queries.
// Sampling: cp=t&7 (2 channels), hs=(t>>3)&7, qgs=t>>6 (2 queries each).
// GEMM/LN:  r=t&127, qb=t>>7 (4 queries each) -- unchanged.
__global__ __launch_bounds__(256, 2)
void attn_kernel(const float* __restrict__ q_in,
                 const float* __restrict__ refpix,
                 const unsigned short* __restrict__ offawT, // [288][len], chunk-local
                 const unsigned short* __restrict__ value,  // [NH][NVPIX][HD]
                 const float* __restrict__ Wout,
                 const float* __restrict__ bout,
                 const float* __restrict__ lng,
                 const float* __restrict__ lnb,
                 const unsigned char* __restrict__ mask,
                 float* __restrict__ dout,
                 int q0g, int len){
    const int n0l = blockIdx.x * 8;         // chunk-local
    const int n0g = q0g + n0l;              // global query index
    const int t = threadIdx.x;
    __shared__ float offaw_s[288][9];
    __shared__ float q_s[8][CDIM];
    __shared__ float out_s[8][CDIM];
    __shared__ float rp_s[16];
    __shared__ float wred[2][4][4];
    __shared__ unsigned char mask_s[8];

    for (int idx = t; idx < 288*8; idx += 256){
        int j = idx >> 3, qi = idx & 7;
        offaw_s[j][qi] = b2f(offawT[(size_t)j*len + n0l + qi]);
    }
    for (int idx = t; idx < 8*CDIM; idx += 256)
        ((float*)q_s)[idx] = q_in[(size_t)n0g*CDIM + idx];
    if (t < 16) rp_s[t] = refpix[n0g*2 + t];
    if (t < 8)  mask_s[t] = mask[n0g + t];
    __syncthreads();

    // softmax over 12 per (query, head): 64 threads
    if (t < 64){
        int qi = t >> 3, h = t & 7;
        float m = -1e30f;
        #pragma unroll
        for (int i=0;i<12;i++) m = fmaxf(m, offaw_s[192+h*12+i][qi]);
        float e[12]; float s = 0.f;
        #pragma unroll
        for (int i=0;i<12;i++){ e[i] = __expf(offaw_s[192+h*12+i][qi]-m); s += e[i]; }
        float is = 1.f/s;
        #pragma unroll
        for (int i=0;i<12;i++) offaw_s[192+h*12+i][qi] = e[i]*is;
    }
    __syncthreads();

    // bilinear sampling: 2 channels x 2 queries per thread, dword gathers
    {
        const int cp  = t & 7;
        const int hs  = (t>>3) & 7;
        const int qgs = t >> 6;             // 0..3
        const unsigned short* vh = value + ((size_t)hs*NVPIX)*HD + cp*2;
        float accv[2][2] = {{0.f,0.f},{0.f,0.f}};
        const int Wl[3]={160,80,40}, Hl[3]={48,24,12}, stl[3]={0,7680,9600};
        #pragma unroll
        for (int l=0;l<3;l++){
            const float fw = (float)Wl[l], fh = (float)Hl[l];
            #pragma unroll 2
            for (int p=0;p<4;p++){
                const int orow = ((hs*3+l)*4+p)*2;
                const int arow = 192 + hs*12 + l*4 + p;
                #pragma unroll
                for (int qi2=0;qi2<2;qi2++){
                    const int qi = qgs*2 + qi2;
                    float x = rp_s[qi*2+0]*fw - 0.5f + offaw_s[orow][qi];
                    float y = rp_s[qi*2+1]*fh - 0.5f + offaw_s[orow+1][qi];
                    float x0f = floorf(x), y0f = floorf(y);
                    float lx = x-x0f, ly = y-y0f;
                    int x0 = (int)x0f, y0 = (int)y0f;
                    bool x0ok = (x0 >= 0) && (x0 < Wl[l]);
                    bool x1ok = (x0+1 >= 0) && (x0+1 < Wl[l]);
                    bool y0ok = (y0 >= 0) && (y0 < Hl[l]);
                    bool y1ok = (y0+1 >= 0) && (y0+1 < Hl[l]);
                    int base = stl[l] + y0*Wl[l] + x0;
                    float c00a=0.f,c00b=0.f,c01a=0.f,c01b=0.f;
                    float c10a=0.f,c10b=0.f,c11a=0.f,c11b=0.f;
                    if (x0ok&&y0ok) ld2(vh + (size_t)base*HD,             c00a, c00b);
                    if (x1ok&&y0ok) ld2(vh + (size_t)(base+1)*HD,         c01a, c01b);
                    if (x0ok&&y1ok) ld2(vh + (size_t)(base+Wl[l])*HD,     c10a, c10b);
                    if (x1ok&&y1ok) ld2(vh + (size_t)(base+Wl[l]+1)*HD,   c11a, c11b);
                    float w00=(1.f-lx)*(1.f-ly), w01=lx*(1.f-ly);
                    float w10=(1.f-lx)*ly,       w11=lx*ly;
                    float s0 = c00a*w00 + c01a*w01 + c10a*w10 + c11a*w11;
                    float s1 = c00b*w00 + c01b*w01 + c10b*w10 + c11b*w11;
                    float aw = offaw_s[arow][qi];
                    accv[qi2][0] = fmaf(aw, s0, accv[qi2][0]);
                    accv[qi2][1] = fmaf(aw, s1, accv[qi2][1]);
                }
            }
        }
        #pragma unroll
        for (int qi2=0;qi2<2;qi2++){
            out_s[qgs*2+qi2][hs*HD + cp*2 + 0] = accv[qi2][0];
            out_s[qgs*2+qi2][hs*HD + cp*2 + 1] = accv[qi2][1];
        }
    }
    __syncthreads();

    // attn = out @ Wout.T + bout, 4 queries per thread (r = t&127)
    const int r = t & 127;
    const int qb = t >> 7;                   // 0..1
    float acc[4];
    { float bb = bout[r];
      #pragma unroll
      for (int qi4=0;qi4<4;qi4++) acc[qi4]=bb; }
    const float4* w4p = (const float4*)(Wout + (size_t)r*CDIM);
    #pragma unroll 8
    for (int kc=0;kc<32;kc++){
        float4 w = w4p[kc];
        #pragma unroll
        for (int qi4=0;qi4<4;qi4++){
            const float* os = out_s[qb*4+qi4];
            acc[qi4] += os[kc*4+0]*w.x + os[kc*4+1]*w.y
                      + os[kc*4+2]*w.z + os[kc*4+3]*w.w;
        }
    }

    // residual + LayerNorm + mask + transposed store
    const int wv = t >> 6;
    float hv[4], sred[4];
    #pragma unroll
    for (int qi4=0;qi4<4;qi4++){ hv[qi4] = q_s[qb*4+qi4][r] + acc[qi4]; sred[qi4]=hv[qi4]; }
    #pragma unroll
    for (int off=32; off>0; off>>=1)
        #pragma unroll
        for (int qi4=0;qi4<4;qi4++) sred[qi4] += __shfl_xor(sred[qi4], off, 64);
    if ((t&63)==0){
        #pragma unroll
        for (int qi4=0;qi4<4;qi4++) wred[0][wv][qi4]=sred[qi4];
    }
    __syncthreads();
    float mu[4], dv[4];
    #pragma unroll
    for (int qi4=0;qi4<4;qi4++){
        mu[qi4] = (wred[0][qb*2][qi4]+wred[0][qb*2+1][qi4]) * (1.f/128.f);
        dv[qi4] = hv[qi4]-mu[qi4];
        sred[qi4] = dv[qi4]*dv[qi4];
    }
    #pragma unroll
    for (int off=32; off>0; off>>=1)
        #pragma unroll
        for (int qi4=0;qi4<4;qi4++) sred[qi4] += __shfl_xor(sred[qi4], off, 64);
    if ((t&63)==0){
        #pragma unroll
        for (int qi4=0;qi4<4;qi4++) wred[1][wv][qi4]=sred[qi4];
    }
    __syncthreads();

    float res[4];
    const float g = lng[r], b = lnb[r];
    #pragma unroll
    for (int qi4=0;qi4<4;qi4++){
        float var = (wred[1][qb*2][qi4]+wred[1][qb*2+1][qi4]) * (1.f/128.f);
        float nv  = dv[qi4] * __frsqrt_rn(var + 1e-5f) * g + b;
        res[qi4] = mask_s[qb*4+qi4] ? nv : q_s[qb*4+qi4][r];
    }
    float4 o; o.x=res[0]; o.y=res[1]; o.z=res[2]; o.w=res[3];
    *(float4*)(dout + (size_t)r*NQ + n0g + qb*4) = o;
}

extern "C" void kernel_launch(void* const* d_in, const int* in_sizes, int n_in,
                              void* d_out, int out_size, void* d_ws, size_t ws_size,
                              hipStream_t stream){
    const float* scene  = (const float*)d_in[0];
    const float* f0     = (const float*)d_in[1];
    const float* f1     = (const float*)d_in[2];
    const float* f2     = (const float*)d_in[3];
    const float* depth  = (const float*)d_in[4];
    const float* K      = (const float*)d_in[5];
    const float* E      = (const float*)d_in[6];
    const float* vorig  = (const float*)d_in[7];
    const float* refpix = (const float*)d_in[8];
    const float* Wv     = (const float*)d_in[9];
    const float* bv     = (const float*)d_in[10];
    const float* Woff   = (const float*)d_in[11];
    const float* boff   = (const float*)d_in[12];
    const float* Wattw  = (const float*)d_in[13];
    const float* battw  = (const float*)d_in[14];
    const float* Wout   = (const float*)d_in[15];
    const float* bout   = (const float*)d_in[16];
    const float* lng    = (const float*)d_in[17];
    const float* lnb    = (const float*)d_in[18];

    char* ws = (char*)d_ws;
    const size_t FIXED = 512 + 131072 + 2580480;           // invm + mask + value
    double*         invm   = (double*)(ws);
    unsigned char*  mask   = (unsigned char*)(ws + 512);
    unsigned short* value  = (unsigned short*)(ws + 512 + 131072);
    unsigned short* offawT = (unsigned short*)(ws + FIXED);

    // Chunk query range so 288*chunk*2 bytes of offawT always fits in ws.
    size_t avail = (ws_size > FIXED) ? (ws_size - FIXED) : 0;
    long long maxq = (long long)(avail / (288*2));
    int chunk = (int)((maxq/64)*64);
    if (chunk > NQ) chunk = NQ;
    if (chunk < 64) chunk = 64;

    hipMemsetAsync(mask, 0, NQ, stream);
    inv_kernel<<<1, 64, 0, stream>>>(K, E, invm);
    mask_kernel<<<(NPIX+255)/256, 256, 0, stream>>>(depth, invm, vorig, mask);
    value_kernel<<<NVPIX/4, 128, 0, stream>>>(f0, f1, f2, Wv, bv, value);

    for (int q0 = 0; q0 < NQ; q0 += chunk){
        int len = (NQ - q0 < chunk) ? (NQ - q0) : chunk;
        offaw_kernel<<<len/64, 256, 0, stream>>>(scene + (size_t)q0*CDIM,
                                                 Woff, boff, Wattw, battw,
                                                 offawT, len);
        attn_kernel<<<len/8, 256, 0, stream>>>(scene, refpix, offawT, value,
                                               Wout, bout, lng, lnb, mask,
                                               (float*)d_out, q0, len);
    }
}

// Round 2
// 1185.648 us; speedup vs baseline: 1.3816x; 1.0677x over previous
//
#include <hip/hip_runtime.h>
#include <hip/hip_bf16.h>
#include <stdint.h>

#define XS 128
#define YS 128
#define ZS 8
#define NQ (XS*YS*ZS)        // 131072 queries
#define CDIM 128
#define NH 8
#define HD 16
#define DH 192
#define DW 640
#define NPIX (DH*DW)
#define NVPIX 10080          // 7680 + 1920 + 480

__device__ __forceinline__ float b2f(unsigned short u){
    union { unsigned int i; float f; } v; v.i = ((unsigned int)u) << 16; return v.f;
}
__device__ __forceinline__ unsigned short f2b(float f){
    __hip_bfloat16 h = __float2bfloat16(f);
    return *reinterpret_cast<unsigned short*>(&h);
}
// load 2 bf16 channels (4B) -> two floats
__device__ __forceinline__ void ld2(const unsigned short* p, float& a, float& b){
    unsigned int u = *reinterpret_cast<const unsigned int*>(p);
    a = b2f((unsigned short)(u & 0xffffu));
    b = b2f((unsigned short)(u >> 16));
}

// ---------------- inverse of K (3x3) and E (4x4), fp64, one thread ----------------
__global__ void inv_kernel(const float* __restrict__ K,
                           const float* __restrict__ E,
                           double* __restrict__ inv_out){
    if (threadIdx.x != 0 || blockIdx.x != 0) return;
    double k[3][3], e[4][4];
    for (int i=0;i<9;i++)  k[i/3][i%3] = (double)K[i];
    for (int i=0;i<16;i++) e[i/4][i%4] = (double)E[i];
    double det = k[0][0]*(k[1][1]*k[2][2]-k[1][2]*k[2][1])
               - k[0][1]*(k[1][0]*k[2][2]-k[1][2]*k[2][0])
               + k[0][2]*(k[1][0]*k[2][1]-k[1][1]*k[2][0]);
    double id = 1.0/det;
    double inv[3][3];
    inv[0][0]=(k[1][1]*k[2][2]-k[1][2]*k[2][1])*id;
    inv[0][1]=(k[0][2]*k[2][1]-k[0][1]*k[2][2])*id;
    inv[0][2]=(k[0][1]*k[1][2]-k[0][2]*k[1][1])*id;
    inv[1][0]=(k[1][2]*k[2][0]-k[1][0]*k[2][2])*id;
    inv[1][1]=(k[0][0]*k[2][2]-k[0][2]*k[2][0])*id;
    inv[1][2]=(k[0][2]*k[1][0]-k[0][0]*k[1][2])*id;
    inv[2][0]=(k[1][0]*k[2][1]-k[1][1]*k[2][0])*id;
    inv[2][1]=(k[0][1]*k[2][0]-k[0][0]*k[2][1])*id;
    inv[2][2]=(k[0][0]*k[1][1]-k[0][1]*k[1][0])*id;
    for (int i=0;i<9;i++) inv_out[i] = inv[i/3][i%3];
    double a[4][8];
    for (int i=0;i<4;i++){ for(int j=0;j<4;j++){ a[i][j]=e[i][j]; a[i][4+j]=(i==j)?1.0:0.0; } }
    for (int c=0;c<4;c++){
        int piv=c; double best=fabs(a[c][c]);
        for (int r=c+1;r<4;r++){ double v=fabs(a[r][c]); if (v>best){best=v;piv=r;} }
        if (piv!=c){ for (int j=0;j<8;j++){ double tmp=a[c][j]; a[c][j]=a[piv][j]; a[piv][j]=tmp; } }
        double pv = 1.0/a[c][c];
        for (int j=0;j<8;j++) a[c][j]*=pv;
        for (int r=0;r<4;r++){
            if (r==c) continue;
            double f=a[r][c];
            for(int j=0;j<8;j++) a[r][j]-=f*a[c][j];
        }
    }
    for (int i=0;i<16;i++) inv_out[9+i] = a[i/4][4 + (i%4)];
}

// ================= fused prep kernel: offaw GEMM(+softmax) | value | mask =================
// Block roles by blockIdx.x: [0, nOff) offaw ; [nOff, nOff+nVal) value ; rest mask.
__global__ __launch_bounds__(256)
void prep_kernel(const float* __restrict__ q_in,      // chunk base
                 const float* __restrict__ Woff,
                 const float* __restrict__ boff,
                 const float* __restrict__ Wattw,
                 const float* __restrict__ battw,
                 unsigned short* __restrict__ offawB, // [len/8][288][8] bf16
                 int nOff, int nVal,
                 const float* __restrict__ f0,
                 const float* __restrict__ f1,
                 const float* __restrict__ f2,
                 const float* __restrict__ Wv,
                 const float* __restrict__ bv,
                 unsigned short* __restrict__ value,  // [NH][NVPIX][HD]
                 const float* __restrict__ depth,
                 const double* __restrict__ invm,
                 const float* __restrict__ vorigin,
                 unsigned char* __restrict__ mask){
    __shared__ float smem[64*129];
    const int t = threadIdx.x;

    if ((int)blockIdx.x < nOff){
        // ---------- offaw: 64 queries, output [288] per query, softmax fused ----------
        const int n0 = blockIdx.x * 64;
        float (*Qs)[129] = (float(*)[129])smem;
        for (int idx = t; idx < 64*CDIM; idx += 256){
            int n = idx >> 7, c = idx & 127;
            Qs[n][c] = q_in[(size_t)(n0+n)*CDIM + c];
        }
        __syncthreads();
        const int w = t >> 6, lane = t & 63;
        const size_t qblk = (size_t)((n0 + lane) >> 3) * 2304;  // 288*8
        const int qsub = lane & 7;
        for (int g = 0; g < 6; ++g){
            const int j0 = w*72 + g*12;
            const float* Wb; const float* bb;
            if (j0 < 192){ Wb = Woff  + (size_t)j0*CDIM;       bb = boff  + j0; }
            else         { Wb = Wattw + (size_t)(j0-192)*CDIM; bb = battw + (j0-192); }
            float acc[12];
            #pragma unroll
            for (int r=0;r<12;r++) acc[r] = bb[r];
            #pragma unroll 2
            for (int kc = 0; kc < 32; ++kc){
                float q0 = Qs[lane][kc*4+0];
                float q1 = Qs[lane][kc*4+1];
                float q2 = Qs[lane][kc*4+2];
                float q3 = Qs[lane][kc*4+3];
                #pragma unroll
                for (int r=0;r<12;r++){
                    float4 w4 = *(const float4*)(Wb + r*CDIM + kc*4);
                    acc[r] += q0*w4.x + q1*w4.y + q2*w4.z + q3*w4.w;
                }
            }
            if (j0 >= 192){
                // one head's 12 logits for this lane's query: softmax in-register
                float m = acc[0];
                #pragma unroll
                for (int r=1;r<12;r++) m = fmaxf(m, acc[r]);
                float s = 0.f;
                #pragma unroll
                for (int r=0;r<12;r++){ acc[r] = __expf(acc[r]-m); s += acc[r]; }
                float is = 1.f/s;
                #pragma unroll
                for (int r=0;r<12;r++) acc[r] *= is;
            }
            #pragma unroll
            for (int r=0;r<12;r++)
                offawB[qblk + (size_t)(j0+r)*8 + qsub] = f2b(acc[r]);
        }
    } else if ((int)blockIdx.x < nOff + nVal){
        // ---------- value: 8 pixels per block (two 128-thread halves) ----------
        const int half = t >> 7, tt = t & 127;
        const int p0 = (blockIdx.x - nOff)*8 + half*4;
        float (*fl)[4] = (float(*)[4])(smem + half*(CDIM*4));
        const float* src; int hw, lp;
        if (p0 < 7680)      { src=f0; hw=7680; lp=p0; }
        else if (p0 < 9600) { src=f1; hw=1920; lp=p0-7680; }
        else                { src=f2; hw=480;  lp=p0-9600; }
        float4 v = *(const float4*)(src + tt*hw + lp);
        fl[tt][0]=v.x; fl[tt][1]=v.y; fl[tt][2]=v.z; fl[tt][3]=v.w;
        __syncthreads();
        float bb = bv[tt];
        float acc[4] = {bb,bb,bb,bb};
        const float4* wrow = (const float4*)(Wv + tt*CDIM);
        #pragma unroll 8
        for (int kc=0; kc<32; ++kc){
            float4 w = wrow[kc];
            #pragma unroll
            for (int u=0;u<4;u++){
                float wu = (u==0)?w.x:(u==1)?w.y:(u==2)?w.z:w.w;
                float4 fv = *(const float4*)fl[kc*4+u];
                acc[0] += fv.x*wu; acc[1] += fv.y*wu; acc[2] += fv.z*wu; acc[3] += fv.w*wu;
            }
        }
        const int hh = tt >> 4, cc = tt & 15;
        #pragma unroll
        for (int i=0;i<4;i++)
            value[((size_t)hh*NVPIX + (size_t)(p0+i))*HD + cc] = f2b(acc[i]);
    } else {
        // ---------- mask ----------
        int tid = (blockIdx.x - nOff - nVal)*256 + t;
        if (tid >= NPIX) return;
        int gx = tid % DW, gy = tid / DW;
        double d  = (double)depth[tid];
        double X0 = (double)gx * d, X1 = (double)gy * d, X2 = d;
        double c0 = invm[0]*X0 + invm[1]*X1 + invm[2]*X2;
        double c1 = invm[3]*X0 + invm[4]*X1 + invm[5]*X2;
        double c2 = invm[6]*X0 + invm[7]*X1 + invm[8]*X2;
        const double* iE = invm + 9;
        double w0 = iE[0]*c0 + iE[1]*c1 + iE[2]*c2  + iE[3];
        double w1 = iE[4]*c0 + iE[5]*c1 + iE[6]*c2  + iE[7];
        double w2 = iE[8]*c0 + iE[9]*c1 + iE[10]*c2 + iE[11];
        double v0 = (w0-(double)vorigin[0])/0.4 - 0.5;
        double v1 = (w1-(double)vorigin[1])/0.4 - 0.5;
        double v2 = ((w2-(double)vorigin[2])/0.4 - 0.5) / 2.0;
        int xi = (int)v0, yi = (int)v1, zi = (int)v2;
        if (xi>=0 && xi<XS && yi>=0 && yi<YS && zi>=0 && zi<ZS)
            mask[(xi*YS + yi)*ZS + zi] = 1;
    }
}

// ---------------- sampling + Wout + LN + mask + transposed store ----------------
// Block: 256 threads, 8 queries.
// Sampling: cp=t&7 (2 channels), hs=(t>>3)&7, qgs=t>>6 (2 queries each).
// GEMM/LN:  r=t&127, qb=t>>7 (4 queries each).
__global__ __launch_bounds__(256, 2)
void attn_kernel(const float* __restrict__ q_in,
                 const float* __restrict__ refpix,
                 const unsigned short* __restrict__ offawB, // [len/8][288][8], chunk-local
                 const unsigned short* __restrict__ value,  // [NH][NVPIX][HD]
                 const float* __restrict__ Wout,
                 const float* __restrict__ bout,
                 const float* __restrict__ lng,
                 const float* __restrict__ lnb,
                 const unsigned char* __restrict__ mask,
                 float* __restrict__ dout,
                 int q0g){
    const int n0l = blockIdx.x * 8;         // chunk-local
    const int n0g = q0g + n0l;              // global query index
    const int t = threadIdx.x;
    __shared__ float offaw_s[288][9];
    __shared__ float q_s[8][CDIM];
    __shared__ float out_s[8][CDIM];
    __shared__ float rp_s[16];
    __shared__ float wred[2][4][4];
    __shared__ unsigned char mask_s[8];

    // coalesced staging: 4608 B contiguous (weights already softmaxed)
    {
        const unsigned int* src = (const unsigned int*)(offawB + (size_t)(n0l>>3)*2304);
        for (int idx = t; idx < 1152; idx += 256){
            unsigned int u = src[idx];
            int j = idx >> 2, qp = (idx & 3)*2;
            offaw_s[j][qp]   = b2f((unsigned short)(u & 0xffffu));
            offaw_s[j][qp+1] = b2f((unsigned short)(u >> 16));
        }
    }
    ((float4*)q_s)[t] = ((const float4*)(q_in + (size_t)n0g*CDIM))[t];
    if (t < 16) rp_s[t] = refpix[n0g*2 + t];
    if (t < 8)  mask_s[t] = mask[n0g + t];
    __syncthreads();

    // bilinear sampling: 2 channels x 2 queries per thread, dword gathers
    {
        const int cp  = t & 7;
        const int hs  = (t>>3) & 7;
        const int qgs = t >> 6;             // 0..3
        const unsigned short* vh = value + ((size_t)hs*NVPIX)*HD + cp*2;
        float accv[2][2] = {{0.f,0.f},{0.f,0.f}};
        const int Wl[3]={160,80,40}, Hl[3]={48,24,12}, stl[3]={0,7680,9600};
        #pragma unroll
        for (int l=0;l<3;l++){
            const float fw = (float)Wl[l], fh = (float)Hl[l];
            #pragma unroll 2
            for (int p=0;p<4;p++){
                const int orow = ((hs*3+l)*4+p)*2;
                const int arow = 192 + hs*12 + l*4 + p;
                #pragma unroll
                for (int qi2=0;qi2<2;qi2++){
                    const int qi = qgs*2 + qi2;
                    float x = rp_s[qi*2+0]*fw - 0.5f + offaw_s[orow][qi];
                    float y = rp_s[qi*2+1]*fh - 0.5f + offaw_s[orow+1][qi];
                    float x0f = floorf(x), y0f = floorf(y);
                    float lx = x-x0f, ly = y-y0f;
                    int x0 = (int)x0f, y0 = (int)y0f;
                    bool x0ok = (x0 >= 0) && (x0 < Wl[l]);
                    bool x1ok = (x0+1 >= 0) && (x0+1 < Wl[l]);
                    bool y0ok = (y0 >= 0) && (y0 < Hl[l]);
                    bool y1ok = (y0+1 >= 0) && (y0+1 < Hl[l]);
                    int base = stl[l] + y0*Wl[l] + x0;
                    float c00a=0.f,c00b=0.f,c01a=0.f,c01b=0.f;
                    float c10a=0.f,c10b=0.f,c11a=0.f,c11b=0.f;
                    if (x0ok&&y0ok) ld2(vh + (size_t)base*HD,             c00a, c00b);
                    if (x1ok&&y0ok) ld2(vh + (size_t)(base+1)*HD,         c01a, c01b);
                    if (x0ok&&y1ok) ld2(vh + (size_t)(base+Wl[l])*HD,     c10a, c10b);
                    if (x1ok&&y1ok) ld2(vh + (size_t)(base+Wl[l]+1)*HD,   c11a, c11b);
                    float w00=(1.f-lx)*(1.f-ly), w01=lx*(1.f-ly);
                    float w10=(1.f-lx)*ly,       w11=lx*ly;
                    float s0 = c00a*w00 + c01a*w01 + c10a*w10 + c11a*w11;
                    float s1 = c00b*w00 + c01b*w01 + c10b*w10 + c11b*w11;
                    float aw = offaw_s[arow][qi];
                    accv[qi2][0] = fmaf(aw, s0, accv[qi2][0]);
                    accv[qi2][1] = fmaf(aw, s1, accv[qi2][1]);
                }
            }
        }
        #pragma unroll
        for (int qi2=0;qi2<2;qi2++){
            out_s[qgs*2+qi2][hs*HD + cp*2 + 0] = accv[qi2][0];
            out_s[qgs*2+qi2][hs*HD + cp*2 + 1] = accv[qi2][1];
        }
    }
    __syncthreads();

    // attn = out @ Wout.T + bout, 4 queries per thread (r = t&127)
    const int r = t & 127;
    const int qb = t >> 7;                   // 0..1
    float acc[4];
    { float bb = bout[r];
      #pragma unroll
      for (int qi4=0;qi4<4;qi4++) acc[qi4]=bb; }
    const float4* w4p = (const float4*)(Wout + (size_t)r*CDIM);
    #pragma unroll 8
    for (int kc=0;kc<32;kc++){
        float4 w = w4p[kc];
        #pragma unroll
        for (int qi4=0;qi4<4;qi4++){
            const float* os = out_s[qb*4+qi4];
            acc[qi4] += os[kc*4+0]*w.x + os[kc*4+1]*w.y
                      + os[kc*4+2]*w.z + os[kc*4+3]*w.w;
        }
    }

    // residual + LayerNorm + mask + transposed store
    const int wv = t >> 6;
    float hv[4], sred[4];
    #pragma unroll
    for (int qi4=0;qi4<4;qi4++){ hv[qi4] = q_s[qb*4+qi4][r] + acc[qi4]; sred[qi4]=hv[qi4]; }
    #pragma unroll
    for (int off=32; off>0; off>>=1)
        #pragma unroll
        for (int qi4=0;qi4<4;qi4++) sred[qi4] += __shfl_xor(sred[qi4], off, 64);
    if ((t&63)==0){
        #pragma unroll
        for (int qi4=0;qi4<4;qi4++) wred[0][wv][qi4]=sred[qi4];
    }
    __syncthreads();
    float mu[4], dv[4];
    #pragma unroll
    for (int qi4=0;qi4<4;qi4++){
        mu[qi4] = (wred[0][qb*2][qi4]+wred[0][qb*2+1][qi4]) * (1.f/128.f);
        dv[qi4] = hv[qi4]-mu[qi4];
        sred[qi4] = dv[qi4]*dv[qi4];
    }
    #pragma unroll
    for (int off=32; off>0; off>>=1)
        #pragma unroll
        for (int qi4=0;qi4<4;qi4++) sred[qi4] += __shfl_xor(sred[qi4], off, 64);
    if ((t&63)==0){
        #pragma unroll
        for (int qi4=0;qi4<4;qi4++) wred[1][wv][qi4]=sred[qi4];
    }
    __syncthreads();

    float res[4];
    const float g = lng[r], b = lnb[r];
    #pragma unroll
    for (int qi4=0;qi4<4;qi4++){
        float var = (wred[1][qb*2][qi4]+wred[1][qb*2+1][qi4]) * (1.f/128.f);
        float nv  = dv[qi4] * __frsqrt_rn(var + 1e-5f) * g + b;
        res[qi4] = mask_s[qb*4+qi4] ? nv : q_s[qb*4+qi4][r];
    }
    float4 o; o.x=res[0]; o.y=res[1]; o.z=res[2]; o.w=res[3];
    *(float4*)(dout + (size_t)r*NQ + n0g + qb*4) = o;
}

extern "C" void kernel_launch(void* const* d_in, const int* in_sizes, int n_in,
                              void* d_out, int out_size, void* d_ws, size_t ws_size,
                              hipStream_t stream){
    const float* scene  = (const float*)d_in[0];
    const float* f0     = (const float*)d_in[1];
    const float* f1     = (const float*)d_in[2];
    const float* f2     = (const float*)d_in[3];
    const float* depth  = (const float*)d_in[4];
    const float* K      = (const float*)d_in[5];
    const float* E      = (const float*)d_in[6];
    const float* vorig  = (const float*)d_in[7];
    const float* refpix = (const float*)d_in[8];
    const float* Wv     = (const float*)d_in[9];
    const float* bv     = (const float*)d_in[10];
    const float* Woff   = (const float*)d_in[11];
    const float* boff   = (const float*)d_in[12];
    const float* Wattw  = (const float*)d_in[13];
    const float* battw  = (const float*)d_in[14];
    const float* Wout   = (const float*)d_in[15];
    const float* bout   = (const float*)d_in[16];
    const float* lng    = (const float*)d_in[17];
    const float* lnb    = (const float*)d_in[18];

    char* ws = (char*)d_ws;
    const size_t FIXED = 512 + 131072 + 2580480;           // invm + mask + value
    double*         invm   = (double*)(ws);
    unsigned char*  mask   = (unsigned char*)(ws + 512);
    unsigned short* value  = (unsigned short*)(ws + 512 + 131072);
    unsigned short* offawB = (unsigned short*)(ws + FIXED);

    // Chunk query range so 288*chunk*2 bytes of offawB always fits in ws.
    size_t avail = (ws_size > FIXED) ? (ws_size - FIXED) : 0;
    long long maxq = (long long)(avail / (288*2));
    int chunk = (int)((maxq/64)*64);
    if (chunk > NQ) chunk = NQ;
    if (chunk < 64) chunk = 64;

    hipMemsetAsync(mask, 0, NQ, stream);
    inv_kernel<<<1, 64, 0, stream>>>(K, E, invm);

    for (int q0 = 0; q0 < NQ; q0 += chunk){
        int len = (NQ - q0 < chunk) ? (NQ - q0) : chunk;
        int nOff  = len/64;
        int nVal  = (q0 == 0) ? (NVPIX/8) : 0;          // 1260
        int nMask = (q0 == 0) ? ((NPIX+255)/256) : 0;   // 480
        prep_kernel<<<nOff + nVal + nMask, 256, 0, stream>>>(
            scene + (size_t)q0*CDIM, Woff, boff, Wattw, battw, offawB,
            nOff, nVal,
            f0, f1, f2, Wv, bv, value,
            depth, invm, vorig, mask);
        attn_kernel<<<len/8, 256, 0, stream>>>(scene, refpix, offawB, value,
                                               Wout, bout, lng, lnb, mask,
                                               (float*)d_out, q0);
    }
}

// Round 3
// 757.297 us; speedup vs baseline: 2.1631x; 1.5656x over previous
//
#include <hip/hip_runtime.h>
#include <hip/hip_bf16.h>
#include <stdint.h>

#define XS 128
#define YS 128
#define ZS 8
#define NQ (XS*YS*ZS)        // 131072 queries
#define CDIM 128
#define NH 8
#define HD 16
#define DH 192
#define DW 640
#define NPIX (DH*DW)
#define NVPIX 10080          // 7680 + 1920 + 480

typedef float f32x4 __attribute__((ext_vector_type(4)));
typedef short s16x8 __attribute__((ext_vector_type(8)));

__device__ __forceinline__ float b2f(unsigned short u){
    union { unsigned int i; float f; } v; v.i = ((unsigned int)u) << 16; return v.f;
}
__device__ __forceinline__ unsigned short f2b(float f){
    __hip_bfloat16 h = __float2bfloat16(f);
    return *reinterpret_cast<unsigned short*>(&h);
}
// load 2 bf16 channels (4B) -> two floats
__device__ __forceinline__ void ld2(const unsigned short* p, float& a, float& b){
    unsigned int u = *reinterpret_cast<const unsigned int*>(p);
    a = b2f((unsigned short)(u & 0xffffu));
    b = b2f((unsigned short)(u >> 16));
}

// ------------- inverse of K/E (1 thread) + Woff/Wattw -> bf16 conversion -------------
__global__ __launch_bounds__(256)
void inv_kernel(const float* __restrict__ K,
                const float* __restrict__ E,
                double* __restrict__ inv_out,
                const float* __restrict__ Woff,
                const float* __restrict__ Wattw,
                unsigned short* __restrict__ Wbf){
    if (blockIdx.x != 0){
        int idx = (blockIdx.x-1)*256 + threadIdx.x;
        if (idx < 24576)      Wbf[idx] = f2b(Woff[idx]);
        else if (idx < 36864) Wbf[idx] = f2b(Wattw[idx-24576]);
        return;
    }
    if (threadIdx.x != 0) return;
    double k[3][3], e[4][4];
    for (int i=0;i<9;i++)  k[i/3][i%3] = (double)K[i];
    for (int i=0;i<16;i++) e[i/4][i%4] = (double)E[i];
    double det = k[0][0]*(k[1][1]*k[2][2]-k[1][2]*k[2][1])
               - k[0][1]*(k[1][0]*k[2][2]-k[1][2]*k[2][0])
               + k[0][2]*(k[1][0]*k[2][1]-k[1][1]*k[2][0]);
    double id = 1.0/det;
    double inv[3][3];
    inv[0][0]=(k[1][1]*k[2][2]-k[1][2]*k[2][1])*id;
    inv[0][1]=(k[0][2]*k[2][1]-k[0][1]*k[2][2])*id;
    inv[0][2]=(k[0][1]*k[1][2]-k[0][2]*k[1][1])*id;
    inv[1][0]=(k[1][2]*k[2][0]-k[1][0]*k[2][2])*id;
    inv[1][1]=(k[0][0]*k[2][2]-k[0][2]*k[2][0])*id;
    inv[1][2]=(k[0][2]*k[1][0]-k[0][0]*k[1][2])*id;
    inv[2][0]=(k[1][0]*k[2][1]-k[1][1]*k[2][0])*id;
    inv[2][1]=(k[0][1]*k[2][0]-k[0][0]*k[2][1])*id;
    inv[2][2]=(k[0][0]*k[1][1]-k[0][1]*k[1][0])*id;
    for (int i=0;i<9;i++) inv_out[i] = inv[i/3][i%3];
    double a[4][8];
    for (int i=0;i<4;i++){ for(int j=0;j<4;j++){ a[i][j]=e[i][j]; a[i][4+j]=(i==j)?1.0:0.0; } }
    for (int c=0;c<4;c++){
        int piv=c; double best=fabs(a[c][c]);
        for (int r=c+1;r<4;r++){ double v=fabs(a[r][c]); if (v>best){best=v;piv=r;} }
        if (piv!=c){ for (int j=0;j<8;j++){ double tmp=a[c][j]; a[c][j]=a[piv][j]; a[piv][j]=tmp; } }
        double pv = 1.0/a[c][c];
        for (int j=0;j<8;j++) a[c][j]*=pv;
        for (int r=0;r<4;r++){
            if (r==c) continue;
            double f=a[r][c];
            for(int j=0;j<8;j++) a[r][j]-=f*a[c][j];
        }
    }
    for (int i=0;i<16;i++) inv_out[9+i] = a[i/4][4 + (i%4)];
}

// ================= fused prep kernel: offaw MFMA-GEMM(+softmax) | value | mask =================
// Block roles by blockIdx.x: [0, nOff) offaw ; [nOff, nOff+nVal) value ; rest mask.
__global__ __launch_bounds__(256)
void prep_kernel(const float* __restrict__ q_in,      // chunk base
                 const unsigned short* __restrict__ Wbf,  // [288][128] bf16
                 const float* __restrict__ boff,
                 const float* __restrict__ battw,
                 unsigned short* __restrict__ offawB, // [len/8][288][8] bf16
                 int nOff, int nVal,
                 const float* __restrict__ f0,
                 const float* __restrict__ f1,
                 const float* __restrict__ f2,
                 const float* __restrict__ Wv,
                 const float* __restrict__ bv,
                 unsigned short* __restrict__ value,  // [NH][NVPIX][HD]
                 const float* __restrict__ depth,
                 const double* __restrict__ invm,
                 const float* __restrict__ vorigin,
                 unsigned char* __restrict__ mask){
    __shared__ __align__(16) unsigned char smem[36864 + 1280];
    const int t = threadIdx.x;

    if ((int)blockIdx.x < nOff){
        // ---------- offaw: 64 queries/block, MFMA 16x16x32 bf16 ----------
        unsigned short* Ob   = (unsigned short*)smem;          // [8][288][8]
        float*          bias = (float*)(smem + 36864);         // [288]
        const int n0 = blockIdx.x * 64;
        for (int idx = t; idx < 288; idx += 256)
            bias[idx] = (idx < 192) ? boff[idx] : battw[idx-192];

        const int w = t >> 6, lane = t & 63, lr = lane & 15, lg = lane >> 4;
        const int qq = w*16 + lr;               // query within block (0..63)

        f32x4 acc[18];
        #pragma unroll
        for (int i=0;i<18;i++) acc[i] = (f32x4){0.f,0.f,0.f,0.f};

        const float* qrow = q_in + (size_t)(n0 + qq)*CDIM;
        #pragma unroll
        for (int ks=0; ks<4; ++ks){
            // B fragment: this lane's query, k = ks*32 + lg*8 .. +7 (fp32 -> bf16 in reg)
            const float* qp = qrow + ks*32 + lg*8;
            float4 qa = *(const float4*)(qp);
            float4 qb = *(const float4*)(qp+4);
            union { s16x8 v; unsigned short s[8]; } bf;
            bf.s[0]=f2b(qa.x); bf.s[1]=f2b(qa.y); bf.s[2]=f2b(qa.z); bf.s[3]=f2b(qa.w);
            bf.s[4]=f2b(qb.x); bf.s[5]=f2b(qb.y); bf.s[6]=f2b(qb.z); bf.s[7]=f2b(qb.w);
            // A fragments: weight rows f = nt*16 + lr, same k slice
            const unsigned short* wp = Wbf + (size_t)lr*CDIM + ks*32 + lg*8;
            #pragma unroll
            for (int nt=0; nt<18; ++nt){
                s16x8 af = *(const s16x8*)(wp + nt*16*CDIM);
                acc[nt] = __builtin_amdgcn_mfma_f32_16x16x32_bf16(af, bf.v, acc[nt], 0, 0, 0);
            }
        }
        __syncthreads();   // bias staged

        // writeback: D col = lane&15 (query), row = lg*4 + r (feature within tile)
        #pragma unroll
        for (int nt=0; nt<18; ++nt){
            #pragma unroll
            for (int r=0; r<4; ++r){
                int f = nt*16 + lg*4 + r;
                float v = acc[nt][r] + bias[f];
                Ob[(qq>>3)*2304 + f*8 + (qq&7)] = f2b(v);
            }
        }
        __syncthreads();

        // softmax over the 12 logits per (query, head): 512 tasks
        for (int task = t; task < 512; task += 256){
            int q = task >> 3, h = task & 7;
            unsigned short* p = Ob + (q>>3)*2304 + (192 + h*12)*8 + (q&7);
            float e[12]; float m = -1e30f;
            #pragma unroll
            for (int i=0;i<12;i++){ e[i] = b2f(p[i*8]); m = fmaxf(m, e[i]); }
            float s = 0.f;
            #pragma unroll
            for (int i=0;i<12;i++){ e[i] = __expf(e[i]-m); s += e[i]; }
            float is = 1.f/s;
            #pragma unroll
            for (int i=0;i<12;i++) p[i*8] = f2b(e[i]*is);
        }
        __syncthreads();

        // coalesced dump: 36864 B -> offawB
        {
            const uint4* src = (const uint4*)Ob;
            uint4* dst = (uint4*)(offawB + (size_t)blockIdx.x * 18432);
            for (int idx = t; idx < 2304; idx += 256) dst[idx] = src[idx];
        }
    } else if ((int)blockIdx.x < nOff + nVal){
        // ---------- value: 8 pixels per block (two 128-thread halves) ----------
        const int half = t >> 7, tt = t & 127;
        const int p0 = (blockIdx.x - nOff)*8 + half*4;
        float (*fl)[4] = (float(*)[4])((float*)smem + half*(CDIM*4));
        const float* src; int hw, lp;
        if (p0 < 7680)      { src=f0; hw=7680; lp=p0; }
        else if (p0 < 9600) { src=f1; hw=1920; lp=p0-7680; }
        else                { src=f2; hw=480;  lp=p0-9600; }
        float4 v = *(const float4*)(src + tt*hw + lp);
        fl[tt][0]=v.x; fl[tt][1]=v.y; fl[tt][2]=v.z; fl[tt][3]=v.w;
        __syncthreads();
        float bb = bv[tt];
        float acc[4] = {bb,bb,bb,bb};
        const float4* wrow = (const float4*)(Wv + tt*CDIM);
        #pragma unroll 8
        for (int kc=0; kc<32; ++kc){
            float4 w = wrow[kc];
            #pragma unroll
            for (int u=0;u<4;u++){
                float wu = (u==0)?w.x:(u==1)?w.y:(u==2)?w.z:w.w;
                float4 fv = *(const float4*)fl[kc*4+u];
                acc[0] += fv.x*wu; acc[1] += fv.y*wu; acc[2] += fv.z*wu; acc[3] += fv.w*wu;
            }
        }
        const int hh = tt >> 4, cc = tt & 15;
        #pragma unroll
        for (int i=0;i<4;i++)
            value[((size_t)hh*NVPIX + (size_t)(p0+i))*HD + cc] = f2b(acc[i]);
    } else {
        // ---------- mask ----------
        int tid = (blockIdx.x - nOff - nVal)*256 + t;
        if (tid >= NPIX) return;
        int gx = tid % DW, gy = tid / DW;
        double d  = (double)depth[tid];
        double X0 = (double)gx * d, X1 = (double)gy * d, X2 = d;
        double c0 = invm[0]*X0 + invm[1]*X1 + invm[2]*X2;
        double c1 = invm[3]*X0 + invm[4]*X1 + invm[5]*X2;
        double c2 = invm[6]*X0 + invm[7]*X1 + invm[8]*X2;
        const double* iE = invm + 9;
        double w0 = iE[0]*c0 + iE[1]*c1 + iE[2]*c2  + iE[3];
        double w1 = iE[4]*c0 + iE[5]*c1 + iE[6]*c2  + iE[7];
        double w2 = iE[8]*c0 + iE[9]*c1 + iE[10]*c2 + iE[11];
        double v0 = (w0-(double)vorigin[0])/0.4 - 0.5;
        double v1 = (w1-(double)vorigin[1])/0.4 - 0.5;
        double v2 = ((w2-(double)vorigin[2])/0.4 - 0.5) / 2.0;
        int xi = (int)v0, yi = (int)v1, zi = (int)v2;
        if (xi>=0 && xi<XS && yi>=0 && yi<YS && zi>=0 && zi<ZS)
            mask[(xi*YS + yi)*ZS + zi] = 1;
    }
}

// ---------------- sampling + Wout + LN + mask + transposed store ----------------
// Block: 256 threads, 8 queries.
// Sampling: cp=t&7 (2 channels), hs=(t>>3)&7, qgs=t>>6 (2 queries each).
// GEMM/LN:  r=t&127, qb=t>>7 (4 queries each).
__global__ __launch_bounds__(256, 2)
void attn_kernel(const float* __restrict__ q_in,
                 const float* __restrict__ refpix,
                 const unsigned short* __restrict__ offawB, // [len/8][288][8], chunk-local
                 const unsigned short* __restrict__ value,  // [NH][NVPIX][HD]
                 const float* __restrict__ Wout,
                 const float* __restrict__ bout,
                 const float* __restrict__ lng,
                 const float* __restrict__ lnb,
                 const unsigned char* __restrict__ mask,
                 float* __restrict__ dout,
                 int q0g){
    const int n0l = blockIdx.x * 8;         // chunk-local
    const int n0g = q0g + n0l;              // global query index
    const int t = threadIdx.x;
    __shared__ float offaw_s[288][9];
    __shared__ float q_s[8][CDIM];
    __shared__ float out_s[8][CDIM];
    __shared__ float rp_s[16];
    __shared__ float wred[2][4][4];
    __shared__ unsigned char mask_s[8];

    // coalesced staging: 4608 B contiguous (weights already softmaxed)
    {
        const unsigned int* src = (const unsigned int*)(offawB + (size_t)(n0l>>3)*2304);
        for (int idx = t; idx < 1152; idx += 256){
            unsigned int u = src[idx];
            int j = idx >> 2, qp = (idx & 3)*2;
            offaw_s[j][qp]   = b2f((unsigned short)(u & 0xffffu));
            offaw_s[j][qp+1] = b2f((unsigned short)(u >> 16));
        }
    }
    ((float4*)q_s)[t] = ((const float4*)(q_in + (size_t)n0g*CDIM))[t];
    if (t < 16) rp_s[t] = refpix[n0g*2 + t];
    if (t < 8)  mask_s[t] = mask[n0g + t];
    __syncthreads();

    // bilinear sampling: 2 channels x 2 queries per thread, dword gathers
    {
        const int cp  = t & 7;
        const int hs  = (t>>3) & 7;
        const int qgs = t >> 6;             // 0..3
        const unsigned short* vh = value + ((size_t)hs*NVPIX)*HD + cp*2;
        float accv[2][2] = {{0.f,0.f},{0.f,0.f}};
        const int Wl[3]={160,80,40}, Hl[3]={48,24,12}, stl[3]={0,7680,9600};
        #pragma unroll
        for (int l=0;l<3;l++){
            const float fw = (float)Wl[l], fh = (float)Hl[l];
            #pragma unroll 2
            for (int p=0;p<4;p++){
                const int orow = ((hs*3+l)*4+p)*2;
                const int arow = 192 + hs*12 + l*4 + p;
                #pragma unroll
                for (int qi2=0;qi2<2;qi2++){
                    const int qi = qgs*2 + qi2;
                    float x = rp_s[qi*2+0]*fw - 0.5f + offaw_s[orow][qi];
                    float y = rp_s[qi*2+1]*fh - 0.5f + offaw_s[orow+1][qi];
                    float x0f = floorf(x), y0f = floorf(y);
                    float lx = x-x0f, ly = y-y0f;
                    int x0 = (int)x0f, y0 = (int)y0f;
                    bool x0ok = (x0 >= 0) && (x0 < Wl[l]);
                    bool x1ok = (x0+1 >= 0) && (x0+1 < Wl[l]);
                    bool y0ok = (y0 >= 0) && (y0 < Hl[l]);
                    bool y1ok = (y0+1 >= 0) && (y0+1 < Hl[l]);
                    int base = stl[l] + y0*Wl[l] + x0;
                    float c00a=0.f,c00b=0.f,c01a=0.f,c01b=0.f;
                    float c10a=0.f,c10b=0.f,c11a=0.f,c11b=0.f;
                    if (x0ok&&y0ok) ld2(vh + (size_t)base*HD,             c00a, c00b);
                    if (x1ok&&y0ok) ld2(vh + (size_t)(base+1)*HD,         c01a, c01b);
                    if (x0ok&&y1ok) ld2(vh + (size_t)(base+Wl[l])*HD,     c10a, c10b);
                    if (x1ok&&y1ok) ld2(vh + (size_t)(base+Wl[l]+1)*HD,   c11a, c11b);
                    float w00=(1.f-lx)*(1.f-ly), w01=lx*(1.f-ly);
                    float w10=(1.f-lx)*ly,       w11=lx*ly;
                    float s0 = c00a*w00 + c01a*w01 + c10a*w10 + c11a*w11;
                    float s1 = c00b*w00 + c01b*w01 + c10b*w10 + c11b*w11;
                    float aw = offaw_s[arow][qi];
                    accv[qi2][0] = fmaf(aw, s0, accv[qi2][0]);
                    accv[qi2][1] = fmaf(aw, s1, accv[qi2][1]);
                }
            }
        }
        #pragma unroll
        for (int qi2=0;qi2<2;qi2++){
            out_s[qgs*2+qi2][hs*HD + cp*2 + 0] = accv[qi2][0];
            out_s[qgs*2+qi2][hs*HD + cp*2 + 1] = accv[qi2][1];
        }
    }
    __syncthreads();

    // attn = out @ Wout.T + bout, 4 queries per thread (r = t&127)
    const int r = t & 127;
    const int qb = t >> 7;                   // 0..1
    float acc[4];
    { float bb = bout[r];
      #pragma unroll
      for (int qi4=0;qi4<4;qi4++) acc[qi4]=bb; }
    const float4* w4p = (const float4*)(Wout + (size_t)r*CDIM);
    #pragma unroll 8
    for (int kc=0;kc<32;kc++){
        float4 w = w4p[kc];
        #pragma unroll
        for (int qi4=0;qi4<4;qi4++){
            const float* os = out_s[qb*4+qi4];
            acc[qi4] += os[kc*4+0]*w.x + os[kc*4+1]*w.y
                      + os[kc*4+2]*w.z + os[kc*4+3]*w.w;
        }
    }

    // residual + LayerNorm + mask + transposed store
    const int wv = t >> 6;
    float hv[4], sred[4];
    #pragma unroll
    for (int qi4=0;qi4<4;qi4++){ hv[qi4] = q_s[qb*4+qi4][r] + acc[qi4]; sred[qi4]=hv[qi4]; }
    #pragma unroll
    for (int off=32; off>0; off>>=1)
        #pragma unroll
        for (int qi4=0;qi4<4;qi4++) sred[qi4] += __shfl_xor(sred[qi4], off, 64);
    if ((t&63)==0){
        #pragma unroll
        for (int qi4=0;qi4<4;qi4++) wred[0][wv][qi4]=sred[qi4];
    }
    __syncthreads();
    float mu[4], dv[4];
    #pragma unroll
    for (int qi4=0;qi4<4;qi4++){
        mu[qi4] = (wred[0][qb*2][qi4]+wred[0][qb*2+1][qi4]) * (1.f/128.f);
        dv[qi4] = hv[qi4]-mu[qi4];
        sred[qi4] = dv[qi4]*dv[qi4];
    }
    #pragma unroll
    for (int off=32; off>0; off>>=1)
        #pragma unroll
        for (int qi4=0;qi4<4;qi4++) sred[qi4] += __shfl_xor(sred[qi4], off, 64);
    if ((t&63)==0){
        #pragma unroll
        for (int qi4=0;qi4<4;qi4++) wred[1][wv][qi4]=sred[qi4];
    }
    __syncthreads();

    float res[4];
    const float g = lng[r], b = lnb[r];
    #pragma unroll
    for (int qi4=0;qi4<4;qi4++){
        float var = (wred[1][qb*2][qi4]+wred[1][qb*2+1][qi4]) * (1.f/128.f);
        float nv  = dv[qi4] * __frsqrt_rn(var + 1e-5f) * g + b;
        res[qi4] = mask_s[qb*4+qi4] ? nv : q_s[qb*4+qi4][r];
    }
    float4 o; o.x=res[0]; o.y=res[1]; o.z=res[2]; o.w=res[3];
    *(float4*)(dout + (size_t)r*NQ + n0g + qb*4) = o;
}

extern "C" void kernel_launch(void* const* d_in, const int* in_sizes, int n_in,
                              void* d_out, int out_size, void* d_ws, size_t ws_size,
                              hipStream_t stream){
    const float* scene  = (const float*)d_in[0];
    const float* f0     = (const float*)d_in[1];
    const float* f1     = (const float*)d_in[2];
    const float* f2     = (const float*)d_in[3];
    const float* depth  = (const float*)d_in[4];
    const float* K      = (const float*)d_in[5];
    const float* E      = (const float*)d_in[6];
    const float* vorig  = (const float*)d_in[7];
    const float* refpix = (const float*)d_in[8];
    const float* Wv     = (const float*)d_in[9];
    const float* bv     = (const float*)d_in[10];
    const float* Woff   = (const float*)d_in[11];
    const float* boff   = (const float*)d_in[12];
    const float* Wattw  = (const float*)d_in[13];
    const float* battw  = (const float*)d_in[14];
    const float* Wout   = (const float*)d_in[15];
    const float* bout   = (const float*)d_in[16];
    const float* lng    = (const float*)d_in[17];
    const float* lnb    = (const float*)d_in[18];

    char* ws = (char*)d_ws;
    // invm(512) + mask(131072) + value(2580480) + Wbf(73728)
    const size_t FIXED = 512 + 131072 + 2580480 + 73728;
    double*         invm   = (double*)(ws);
    unsigned char*  mask   = (unsigned char*)(ws + 512);
    unsigned short* value  = (unsigned short*)(ws + 512 + 131072);
    unsigned short* Wbf    = (unsigned short*)(ws + 512 + 131072 + 2580480);
    unsigned short* offawB = (unsigned short*)(ws + FIXED);

    // Chunk query range so 288*chunk*2 bytes of offawB always fits in ws.
    size_t avail = (ws_size > FIXED) ? (ws_size - FIXED) : 0;
    long long maxq = (long long)(avail / (288*2));
    int chunk = (int)((maxq/64)*64);
    if (chunk > NQ) chunk = NQ;
    if (chunk < 64) chunk = 64;

    hipMemsetAsync(mask, 0, NQ, stream);
    inv_kernel<<<145, 256, 0, stream>>>(K, E, invm, Woff, Wattw, Wbf);

    for (int q0 = 0; q0 < NQ; q0 += chunk){
        int len = (NQ - q0 < chunk) ? (NQ - q0) : chunk;
        int nOff  = len/64;
        int nVal  = (q0 == 0) ? (NVPIX/8) : 0;          // 1260
        int nMask = (q0 == 0) ? ((NPIX+255)/256) : 0;   // 480
        prep_kernel<<<nOff + nVal + nMask, 256, 0, stream>>>(
            scene + (size_t)q0*CDIM, Wbf, boff, battw, offawB,
            nOff, nVal,
            f0, f1, f2, Wv, bv, value,
            depth, invm, vorig, mask);
        attn_kernel<<<len/8, 256, 0, stream>>>(scene, refpix, offawB, value,
                                               Wout, bout, lng, lnb, mask,
                                               (float*)d_out, q0);
    }
}

// Round 4
// 468.177 us; speedup vs baseline: 3.4990x; 1.6175x over previous
//
#include <hip/hip_runtime.h>
#include <hip/hip_bf16.h>
#include <stdint.h>

#define XS 128
#define YS 128
#define ZS 8
#define NQ (XS*YS*ZS)        // 131072 queries
#define CDIM 128
#define NH 8
#define HD 16
#define DH 192
#define DW 640
#define NPIX (DH*DW)
#define NVPIX 10080          // 7680 + 1920 + 480

typedef float f32x4 __attribute__((ext_vector_type(4)));
typedef short s16x8 __attribute__((ext_vector_type(8)));

__device__ __forceinline__ float b2f(unsigned short u){
    union { unsigned int i; float f; } v; v.i = ((unsigned int)u) << 16; return v.f;
}
__device__ __forceinline__ unsigned short f2b(float f){
    __hip_bfloat16 h = __float2bfloat16(f);
    return *reinterpret_cast<unsigned short*>(&h);
}
__device__ __forceinline__ float blo(unsigned int u){
    union { unsigned int i; float f; } v; v.i = u << 16; return v.f;
}
__device__ __forceinline__ float bhi(unsigned int u){
    union { unsigned int i; float f; } v; v.i = u & 0xffff0000u; return v.f;
}

// ------------- inverse of K/E (1 thread) + Woff/Wattw/Wout -> bf16 conversion -------------
__global__ __launch_bounds__(256)
void inv_kernel(const float* __restrict__ K,
                const float* __restrict__ E,
                double* __restrict__ inv_out,
                const float* __restrict__ Woff,
                const float* __restrict__ Wattw,
                const float* __restrict__ Wout,
                unsigned short* __restrict__ Wbf){
    if (blockIdx.x != 0){
        int idx = (blockIdx.x-1)*256 + threadIdx.x;
        if (idx < 24576)      Wbf[idx] = f2b(Woff[idx]);
        else if (idx < 36864) Wbf[idx] = f2b(Wattw[idx-24576]);
        else if (idx < 53248) Wbf[idx] = f2b(Wout[idx-36864]);
        return;
    }
    if (threadIdx.x != 0) return;
    double k[3][3], e[4][4];
    for (int i=0;i<9;i++)  k[i/3][i%3] = (double)K[i];
    for (int i=0;i<16;i++) e[i/4][i%4] = (double)E[i];
    double det = k[0][0]*(k[1][1]*k[2][2]-k[1][2]*k[2][1])
               - k[0][1]*(k[1][0]*k[2][2]-k[1][2]*k[2][0])
               + k[0][2]*(k[1][0]*k[2][1]-k[1][1]*k[2][0]);
    double id = 1.0/det;
    double inv[3][3];
    inv[0][0]=(k[1][1]*k[2][2]-k[1][2]*k[2][1])*id;
    inv[0][1]=(k[0][2]*k[2][1]-k[0][1]*k[2][2])*id;
    inv[0][2]=(k[0][1]*k[1][2]-k[0][2]*k[1][1])*id;
    inv[1][0]=(k[1][2]*k[2][0]-k[1][0]*k[2][2])*id;
    inv[1][1]=(k[0][0]*k[2][2]-k[0][2]*k[2][0])*id;
    inv[1][2]=(k[0][2]*k[1][0]-k[0][0]*k[1][2])*id;
    inv[2][0]=(k[1][0]*k[2][1]-k[1][1]*k[2][0])*id;
    inv[2][1]=(k[0][1]*k[2][0]-k[0][0]*k[2][1])*id;
    inv[2][2]=(k[0][0]*k[1][1]-k[0][1]*k[1][0])*id;
    for (int i=0;i<9;i++) inv_out[i] = inv[i/3][i%3];
    double a[4][8];
    for (int i=0;i<4;i++){ for(int j=0;j<4;j++){ a[i][j]=e[i][j]; a[i][4+j]=(i==j)?1.0:0.0; } }
    for (int c=0;c<4;c++){
        int piv=c; double best=fabs(a[c][c]);
        for (int r=c+1;r<4;r++){ double v=fabs(a[r][c]); if (v>best){best=v;piv=r;} }
        if (piv!=c){ for (int j=0;j<8;j++){ double tmp=a[c][j]; a[c][j]=a[piv][j]; a[piv][j]=tmp; } }
        double pv = 1.0/a[c][c];
        for (int j=0;j<8;j++) a[c][j]*=pv;
        for (int r=0;r<4;r++){
            if (r==c) continue;
            double f=a[r][c];
            for(int j=0;j<8;j++) a[r][j]-=f*a[c][j];
        }
    }
    for (int i=0;i<16;i++) inv_out[9+i] = a[i/4][4 + (i%4)];
}

// ================= fused prep kernel: offaw MFMA-GEMM(+softmax) | value | mask =================
__global__ __launch_bounds__(256)
void prep_kernel(const float* __restrict__ q_in,      // chunk base
                 const unsigned short* __restrict__ Wbf,  // [288][128] bf16
                 const float* __restrict__ boff,
                 const float* __restrict__ battw,
                 unsigned short* __restrict__ offawB, // [len/8][288][8] bf16
                 int nOff, int nVal,
                 const float* __restrict__ f0,
                 const float* __restrict__ f1,
                 const float* __restrict__ f2,
                 const float* __restrict__ Wv,
                 const float* __restrict__ bv,
                 unsigned short* __restrict__ value,  // [NH][NVPIX][HD]
                 const float* __restrict__ depth,
                 const double* __restrict__ invm,
                 const float* __restrict__ vorigin,
                 unsigned char* __restrict__ mask){
    __shared__ __align__(16) unsigned char smem[36864 + 1280];
    const int t = threadIdx.x;

    if ((int)blockIdx.x < nOff){
        // ---------- offaw: 64 queries/block, MFMA 16x16x32 bf16 ----------
        unsigned short* Ob   = (unsigned short*)smem;          // [8][288][8]
        float*          bias = (float*)(smem + 36864);         // [288]
        const int n0 = blockIdx.x * 64;
        for (int idx = t; idx < 288; idx += 256)
            bias[idx] = (idx < 192) ? boff[idx] : battw[idx-192];

        const int w = t >> 6, lane = t & 63, lr = lane & 15, lg = lane >> 4;
        const int qq = w*16 + lr;               // query within block (0..63)

        f32x4 acc[18];
        #pragma unroll
        for (int i=0;i<18;i++) acc[i] = (f32x4){0.f,0.f,0.f,0.f};

        const float* qrow = q_in + (size_t)(n0 + qq)*CDIM;
        #pragma unroll
        for (int ks=0; ks<4; ++ks){
            const float* qp = qrow + ks*32 + lg*8;
            float4 qa = *(const float4*)(qp);
            float4 qb = *(const float4*)(qp+4);
            union { s16x8 v; unsigned short s[8]; } bf;
            bf.s[0]=f2b(qa.x); bf.s[1]=f2b(qa.y); bf.s[2]=f2b(qa.z); bf.s[3]=f2b(qa.w);
            bf.s[4]=f2b(qb.x); bf.s[5]=f2b(qb.y); bf.s[6]=f2b(qb.z); bf.s[7]=f2b(qb.w);
            const unsigned short* wp = Wbf + (size_t)lr*CDIM + ks*32 + lg*8;
            #pragma unroll
            for (int nt=0; nt<18; ++nt){
                s16x8 af = *(const s16x8*)(wp + nt*16*CDIM);
                acc[nt] = __builtin_amdgcn_mfma_f32_16x16x32_bf16(af, bf.v, acc[nt], 0, 0, 0);
            }
        }
        __syncthreads();   // bias staged

        #pragma unroll
        for (int nt=0; nt<18; ++nt){
            #pragma unroll
            for (int r=0; r<4; ++r){
                int f = nt*16 + lg*4 + r;
                float v = acc[nt][r] + bias[f];
                Ob[(qq>>3)*2304 + f*8 + (qq&7)] = f2b(v);
            }
        }
        __syncthreads();

        // softmax over the 12 logits per (query, head): 512 tasks
        for (int task = t; task < 512; task += 256){
            int q = task >> 3, h = task & 7;
            unsigned short* p = Ob + (q>>3)*2304 + (192 + h*12)*8 + (q&7);
            float e[12]; float m = -1e30f;
            #pragma unroll
            for (int i=0;i<12;i++){ e[i] = b2f(p[i*8]); m = fmaxf(m, e[i]); }
            float s = 0.f;
            #pragma unroll
            for (int i=0;i<12;i++){ e[i] = __expf(e[i]-m); s += e[i]; }
            float is = 1.f/s;
            #pragma unroll
            for (int i=0;i<12;i++) p[i*8] = f2b(e[i]*is);
        }
        __syncthreads();

        // coalesced dump: 36864 B -> offawB
        {
            const uint4* src = (const uint4*)Ob;
            uint4* dst = (uint4*)(offawB + (size_t)blockIdx.x * 18432);
            for (int idx = t; idx < 2304; idx += 256) dst[idx] = src[idx];
        }
    } else if ((int)blockIdx.x < nOff + nVal){
        // ---------- value: 8 pixels per block (two 128-thread halves) ----------
        const int half = t >> 7, tt = t & 127;
        const int p0 = (blockIdx.x - nOff)*8 + half*4;
        float (*fl)[4] = (float(*)[4])((float*)smem + half*(CDIM*4));
        const float* src; int hw, lp;
        if (p0 < 7680)      { src=f0; hw=7680; lp=p0; }
        else if (p0 < 9600) { src=f1; hw=1920; lp=p0-7680; }
        else                { src=f2; hw=480;  lp=p0-9600; }
        float4 v = *(const float4*)(src + tt*hw + lp);
        fl[tt][0]=v.x; fl[tt][1]=v.y; fl[tt][2]=v.z; fl[tt][3]=v.w;
        __syncthreads();
        float bb = bv[tt];
        float acc[4] = {bb,bb,bb,bb};
        const float4* wrow = (const float4*)(Wv + tt*CDIM);
        #pragma unroll 8
        for (int kc=0; kc<32; ++kc){
            float4 w = wrow[kc];
            #pragma unroll
            for (int u=0;u<4;u++){
                float wu = (u==0)?w.x:(u==1)?w.y:(u==2)?w.z:w.w;
                float4 fv = *(const float4*)fl[kc*4+u];
                acc[0] += fv.x*wu; acc[1] += fv.y*wu; acc[2] += fv.z*wu; acc[3] += fv.w*wu;
            }
        }
        const int hh = tt >> 4, cc = tt & 15;
        #pragma unroll
        for (int i=0;i<4;i++)
            value[((size_t)hh*NVPIX + (size_t)(p0+i))*HD + cc] = f2b(acc[i]);
    } else {
        // ---------- mask ----------
        int tid = (blockIdx.x - nOff - nVal)*256 + t;
        if (tid >= NPIX) return;
        int gx = tid % DW, gy = tid / DW;
        double d  = (double)depth[tid];
        double X0 = (double)gx * d, X1 = (double)gy * d, X2 = d;
        double c0 = invm[0]*X0 + invm[1]*X1 + invm[2]*X2;
        double c1 = invm[3]*X0 + invm[4]*X1 + invm[5]*X2;
        double c2 = invm[6]*X0 + invm[7]*X1 + invm[8]*X2;
        const double* iE = invm + 9;
        double w0 = iE[0]*c0 + iE[1]*c1 + iE[2]*c2  + iE[3];
        double w1 = iE[4]*c0 + iE[5]*c1 + iE[6]*c2  + iE[7];
        double w2 = iE[8]*c0 + iE[9]*c1 + iE[10]*c2 + iE[11];
        double v0 = (w0-(double)vorigin[0])/0.4 - 0.5;
        double v1 = (w1-(double)vorigin[1])/0.4 - 0.5;
        double v2 = ((w2-(double)vorigin[2])/0.4 - 0.5) / 2.0;
        int xi = (int)v0, yi = (int)v1, zi = (int)v2;
        if (xi>=0 && xi<XS && yi>=0 && yi<YS && zi>=0 && zi<ZS)
            mask[(xi*YS + yi)*ZS + zi] = 1;
    }
}

// ---------------- sampling + Wout(MFMA) + LN + mask + transposed store ----------------
// LDS byte map (25296 total):
//   0     raw[288][8] bf16 staged offawB      (4608)
//   4608  desc[768] uint4 (swizzled)          (12288)   [aliased by out2[8][128] f32 after sampling]
//   16896 obf[16][128] bf16 (swizzled)        (4096)
//   20992 q_s[8][128] f32                     (4096)
//   25088 rp_s[16] f32                        (64)
//   25152 wred[2][4][4] f32                   (128)
//   25280 mask_s[8]                           (16)
__global__ __launch_bounds__(256, 2)
void attn_kernel(const float* __restrict__ q_in,
                 const float* __restrict__ refpix,
                 const unsigned short* __restrict__ offawB, // [len/8][288][8], chunk-local
                 const unsigned short* __restrict__ value,  // [NH][NVPIX][HD]
                 const unsigned short* __restrict__ WoutBf, // [128][128] bf16
                 const float* __restrict__ bout,
                 const float* __restrict__ lng,
                 const float* __restrict__ lnb,
                 const unsigned char* __restrict__ mask,
                 float* __restrict__ dout,
                 int q0g){
    const int n0l = blockIdx.x * 8;         // chunk-local
    const int n0g = q0g + n0l;              // global query index
    const int t = threadIdx.x;
    __shared__ __align__(16) unsigned char smem[25296];
    unsigned short* raw   = (unsigned short*)(smem);
    unsigned char*  descB = smem + 4608;
    float*          out2  = (float*)(smem + 4608);          // alias over desc
    unsigned char*  obfB  = smem + 16896;
    float (*q_s)[CDIM]    = (float(*)[CDIM])(smem + 20992);
    float*          rp_s  = (float*)(smem + 25088);
    float*          wredp = (float*)(smem + 25152);         // [2][4][4]
    unsigned char*  mask_s= (unsigned char*)(smem + 25280);

    // ---- stage ----
    {
        const unsigned int* src = (const unsigned int*)(offawB + (size_t)(n0l>>3)*2304);
        unsigned int* dst = (unsigned int*)raw;
        #pragma unroll
        for (int i=0;i<5;i++){ int idx = t + i*256; if (idx < 1152) dst[idx] = src[idx]; }
        ((float4*)q_s)[t] = ((const float4*)(q_in + (size_t)n0g*CDIM))[t];
        ((unsigned int*)obfB)[512 + t] = 0;   // zero obf rows 8..15
        ((unsigned int*)obfB)[768 + t] = 0;
        if (t < 16) rp_s[t] = refpix[n0g*2 + t];
        if (t < 8)  mask_s[t] = mask[n0g + t];
    }
    __syncthreads();

    // ---- Phase A: 768 sample descriptors (hp = h*12 + l*4 + p; idx = hp*8 + q) ----
    for (int idx = t; idx < 768; idx += 256){
        int q = idx & 7, hp = idx >> 3;
        int lp = hp % 12;
        float fw, fh; int Wl, Hl, st;
        if (lp < 4)      { fw=160.f; fh=48.f; Wl=160; Hl=48; st=0; }
        else if (lp < 8) { fw=80.f;  fh=24.f; Wl=80;  Hl=24; st=7680; }
        else             { fw=40.f;  fh=12.f; Wl=40;  Hl=12; st=9600; }
        float offx = b2f(raw[(hp*2)*8 + q]);
        float offy = b2f(raw[(hp*2+1)*8 + q]);
        float aw   = b2f(raw[(192+hp)*8 + q]);
        float x = rp_s[q*2+0]*fw - 0.5f + offx;
        float y = rp_s[q*2+1]*fh - 0.5f + offy;
        float x0f = floorf(x), y0f = floorf(y);
        float lx = x-x0f, ly = y-y0f;
        int x0 = (int)x0f, y0 = (int)y0f;
        bool x0ok = (x0>=0)&&(x0<Wl), x1ok=(x0+1>=0)&&(x0+1<Wl);
        bool y0ok = (y0>=0)&&(y0<Hl), y1ok=(y0+1>=0)&&(y0+1<Hl);
        float w00 = (x0ok&&y0ok)? (1.f-lx)*(1.f-ly)*aw : 0.f;
        float w01 = (x1ok&&y0ok)? lx*(1.f-ly)*aw       : 0.f;
        float w10 = (x0ok&&y1ok)? (1.f-lx)*ly*aw       : 0.f;
        float w11 = (x1ok&&y1ok)? lx*ly*aw             : 0.f;
        int yc0 = min(max(y0,0),Hl-1), yc1 = min(max(y0+1,0),Hl-1);
        int xc0 = min(max(x0,0),Wl-1), xc1 = min(max(x0+1,0),Wl-1);
        unsigned int rb0 = (unsigned int)(st + yc0*Wl), rb1 = (unsigned int)(st + yc1*Wl);
        uint4 d;
        d.x = (rb0+(unsigned int)xc0) | ((rb0+(unsigned int)xc1)<<16);
        d.y = (rb1+(unsigned int)xc0) | ((rb1+(unsigned int)xc1)<<16);
        d.z = (unsigned int)f2b(w00) | ((unsigned int)f2b(w01)<<16);
        d.w = (unsigned int)f2b(w10) | ((unsigned int)f2b(w11)<<16);
        *(uint4*)(descB + (((unsigned int)(idx ^ ((idx>>5)&7)))<<4)) = d;
    }
    __syncthreads();

    // ---- sampling: 2 channels x 2 queries per thread, unconditional dword gathers ----
    {
        const int cp = t & 7, hs = (t>>3) & 7, qgs = t >> 6;
        const unsigned short* vh = value + ((size_t)hs*NVPIX)*HD + cp*2;
        float av0x=0.f, av0y=0.f, av1x=0.f, av1y=0.f;
        #pragma unroll
        for (int lp=0; lp<12; ++lp){
            #pragma unroll
            for (int qi2=0; qi2<2; ++qi2){
                int idx = (hs*12+lp)*8 + qgs*2 + qi2;
                uint4 d = *(const uint4*)(descB + (((unsigned int)(idx ^ ((idx>>5)&7)))<<4));
                unsigned int p00 = d.x & 0xffffu, p01 = d.x >> 16;
                unsigned int p10 = d.y & 0xffffu, p11 = d.y >> 16;
                unsigned int u00 = *(const unsigned int*)(vh + (p00<<4));
                unsigned int u01 = *(const unsigned int*)(vh + (p01<<4));
                unsigned int u10 = *(const unsigned int*)(vh + (p10<<4));
                unsigned int u11 = *(const unsigned int*)(vh + (p11<<4));
                float w00 = blo(d.z), w01 = bhi(d.z), w10 = blo(d.w), w11 = bhi(d.w);
                float sx = blo(u00)*w00 + blo(u01)*w01 + blo(u10)*w10 + blo(u11)*w11;
                float sy = bhi(u00)*w00 + bhi(u01)*w01 + bhi(u10)*w10 + bhi(u11)*w11;
                if (qi2 == 0){ av0x += sx; av0y += sy; }
                else         { av1x += sx; av1y += sy; }
            }
        }
        // write bf16 pair into swizzled obf[q][hs*16+cp*2]
        const int q0q = qgs*2;
        unsigned int pk0 = (unsigned int)f2b(av0x) | ((unsigned int)f2b(av0y)<<16);
        unsigned int pk1 = (unsigned int)f2b(av1x) | ((unsigned int)f2b(av1y)<<16);
        unsigned int bo0 = (unsigned int)(q0q*256 + hs*32 + cp*4)     ^ (unsigned int)((q0q&7)<<4);
        unsigned int bo1 = (unsigned int)((q0q+1)*256 + hs*32 + cp*4) ^ (unsigned int)(((q0q+1)&7)<<4);
        *(unsigned int*)(obfB + bo0) = pk0;
        *(unsigned int*)(obfB + bo1) = pk1;
    }
    __syncthreads();

    // ---- Wout projection via MFMA: D[f][q] = Wout[f] . out[q], bout folded ----
    {
        const int w = t >> 6, lane = t & 63, lr = lane & 15, lg = lane >> 4;
        f32x4 a0 = (f32x4){0.f,0.f,0.f,0.f};
        f32x4 a1 = (f32x4){0.f,0.f,0.f,0.f};
        #pragma unroll
        for (int ks=0; ks<4; ++ks){
            unsigned int bo = (unsigned int)(lr*256 + ks*64 + lg*16) ^ (unsigned int)((lr&7)<<4);
            s16x8 bfrag = *(const s16x8*)(obfB + bo);
            const unsigned short* wp = WoutBf + (size_t)(w*32 + lr)*CDIM + ks*32 + lg*8;
            s16x8 af0 = *(const s16x8*)(wp);
            s16x8 af1 = *(const s16x8*)(wp + 16*CDIM);
            a0 = __builtin_amdgcn_mfma_f32_16x16x32_bf16(af0, bfrag, a0, 0, 0, 0);
            a1 = __builtin_amdgcn_mfma_f32_16x16x32_bf16(af1, bfrag, a1, 0, 0, 0);
        }
        if (lr < 8){
            int f0 = w*32 + lg*4;
            float4 b0 = *(const float4*)(bout + f0);
            float4 b1 = *(const float4*)(bout + f0 + 16);
            float4 v0, v1;
            v0.x = a0[0]+b0.x; v0.y = a0[1]+b0.y; v0.z = a0[2]+b0.z; v0.w = a0[3]+b0.w;
            v1.x = a1[0]+b1.x; v1.y = a1[1]+b1.y; v1.z = a1[2]+b1.z; v1.w = a1[3]+b1.w;
            *(float4*)(out2 + lr*CDIM + f0)      = v0;
            *(float4*)(out2 + lr*CDIM + f0 + 16) = v1;
        }
    }
    __syncthreads();

    // ---- residual + LayerNorm + mask + transposed store ----
    const int r = t & 127;
    const int qb = t >> 7;                   // 0..1
    const int wv = t >> 6;
    float acc[4];
    #pragma unroll
    for (int qi4=0;qi4<4;qi4++) acc[qi4] = out2[(qb*4+qi4)*CDIM + r];

    float hv[4], sred[4];
    #pragma unroll
    for (int qi4=0;qi4<4;qi4++){ hv[qi4] = q_s[qb*4+qi4][r] + acc[qi4]; sred[qi4]=hv[qi4]; }
    #pragma unroll
    for (int off=32; off>0; off>>=1)
        #pragma unroll
        for (int qi4=0;qi4<4;qi4++) sred[qi4] += __shfl_xor(sred[qi4], off, 64);
    if ((t&63)==0){
        #pragma unroll
        for (int qi4=0;qi4<4;qi4++) wredp[0*16 + wv*4 + qi4]=sred[qi4];
    }
    __syncthreads();
    float mu[4], dv[4];
    #pragma unroll
    for (int qi4=0;qi4<4;qi4++){
        mu[qi4] = (wredp[0*16 + (qb*2)*4 + qi4]+wredp[0*16 + (qb*2+1)*4 + qi4]) * (1.f/128.f);
        dv[qi4] = hv[qi4]-mu[qi4];
        sred[qi4] = dv[qi4]*dv[qi4];
    }
    #pragma unroll
    for (int off=32; off>0; off>>=1)
        #pragma unroll
        for (int qi4=0;qi4<4;qi4++) sred[qi4] += __shfl_xor(sred[qi4], off, 64);
    if ((t&63)==0){
        #pragma unroll
        for (int qi4=0;qi4<4;qi4++) wredp[1*16 + wv*4 + qi4]=sred[qi4];
    }
    __syncthreads();

    float res[4];
    const float g = lng[r], b = lnb[r];
    #pragma unroll
    for (int qi4=0;qi4<4;qi4++){
        float var = (wredp[1*16 + (qb*2)*4 + qi4]+wredp[1*16 + (qb*2+1)*4 + qi4]) * (1.f/128.f);
        float nv  = dv[qi4] * __frsqrt_rn(var + 1e-5f) * g + b;
        res[qi4] = mask_s[qb*4+qi4] ? nv : q_s[qb*4+qi4][r];
    }
    float4 o; o.x=res[0]; o.y=res[1]; o.z=res[2]; o.w=res[3];
    *(float4*)(dout + (size_t)r*NQ + n0g + qb*4) = o;
}

extern "C" void kernel_launch(void* const* d_in, const int* in_sizes, int n_in,
                              void* d_out, int out_size, void* d_ws, size_t ws_size,
                              hipStream_t stream){
    const float* scene  = (const float*)d_in[0];
    const float* f0     = (const float*)d_in[1];
    const float* f1     = (const float*)d_in[2];
    const float* f2     = (const float*)d_in[3];
    const float* depth  = (const float*)d_in[4];
    const float* K      = (const float*)d_in[5];
    const float* E      = (const float*)d_in[6];
    const float* vorig  = (const float*)d_in[7];
    const float* refpix = (const float*)d_in[8];
    const float* Wv     = (const float*)d_in[9];
    const float* bv     = (const float*)d_in[10];
    const float* Woff   = (const float*)d_in[11];
    const float* boff   = (const float*)d_in[12];
    const float* Wattw  = (const float*)d_in[13];
    const float* battw  = (const float*)d_in[14];
    const float* Wout   = (const float*)d_in[15];
    const float* bout   = (const float*)d_in[16];
    const float* lng    = (const float*)d_in[17];
    const float* lnb    = (const float*)d_in[18];

    char* ws = (char*)d_ws;
    // invm(512) + mask(131072) + value(2580480) + Wbf(106496: Woff|Wattw|Wout bf16)
    const size_t FIXED = 512 + 131072 + 2580480 + 106496;
    double*         invm   = (double*)(ws);
    unsigned char*  mask   = (unsigned char*)(ws + 512);
    unsigned short* value  = (unsigned short*)(ws + 512 + 131072);
    unsigned short* Wbf    = (unsigned short*)(ws + 512 + 131072 + 2580480);
    unsigned short* WoutBf = Wbf + 36864;
    unsigned short* offawB = (unsigned short*)(ws + FIXED);

    // Chunk query range so 288*chunk*2 bytes of offawB always fits in ws.
    size_t avail = (ws_size > FIXED) ? (ws_size - FIXED) : 0;
    long long maxq = (long long)(avail / (288*2));
    int chunk = (int)((maxq/64)*64);
    if (chunk > NQ) chunk = NQ;
    if (chunk < 64) chunk = 64;

    hipMemsetAsync(mask, 0, NQ, stream);
    inv_kernel<<<209, 256, 0, stream>>>(K, E, invm, Woff, Wattw, Wout, Wbf);

    for (int q0 = 0; q0 < NQ; q0 += chunk){
        int len = (NQ - q0 < chunk) ? (NQ - q0) : chunk;
        int nOff  = len/64;
        int nVal  = (q0 == 0) ? (NVPIX/8) : 0;          // 1260
        int nMask = (q0 == 0) ? ((NPIX+255)/256) : 0;   // 480
        prep_kernel<<<nOff + nVal + nMask, 256, 0, stream>>>(
            scene + (size_t)q0*CDIM, Wbf, boff, battw, offawB,
            nOff, nVal,
            f0, f1, f2, Wv, bv, value,
            depth, invm, vorig, mask);
        attn_kernel<<<len/8, 256, 0, stream>>>(scene, refpix, offawB, value,
                                               WoutBf, bout, lng, lnb, mask,
                                               (float*)d_out, q0);
    }
}